// Round 3
// baseline (10967.032 us; speedup 1.0000x reference)
//
#include <hip/hip_runtime.h>
#include <hip/hip_bf16.h>

#define N_NODES 50000
#define N_EDGES 800000
#define N_GRAPH 500
#define ND 64
#define ED 32
#define HD 128
#define WPB 4   // waves per block (256 threads)

__device__ __forceinline__ float sp(float x) {
    // softplus = log1p(exp(x)), numerically stable
    return fmaxf(x, 0.f) + log1pf(expf(-fabsf(x)));
}

// t[i][j] = softplus(x[i]@Wnp + bnp)[j]; accumulate column sums/sumsq for BN
__global__ __launch_bounds__(256) void k_node_proj(
    const float* __restrict__ x, const float* __restrict__ Wnp,
    const float* __restrict__ bnp, float* __restrict__ t,
    float* __restrict__ stats) {
    int lane = threadIdx.x & 63;
    int wave = (blockIdx.x * blockDim.x + threadIdx.x) >> 6;
    int nw = (gridDim.x * blockDim.x) >> 6;
    float w[13];
#pragma unroll
    for (int k = 0; k < 13; ++k) w[k] = Wnp[k * ND + lane];
    float bb = bnp[lane];
    float s0 = 0.f, s1 = 0.f;
    for (int i = wave; i < N_NODES; i += nw) {
        float acc = bb;
#pragma unroll
        for (int k = 0; k < 13; ++k) acc += x[i * 13 + k] * w[k];
        float v = sp(acc);
        t[i * ND + lane] = v;
        s0 += v; s1 += v * v;
    }
    atomicAdd(&stats[lane], s0);
    atomicAdd(&stats[ND + lane], s1);
}

// scale/shift from stats: h = t*scale + shift == (t-mu)*rsqrt(var+eps)*g + b
__global__ void k_bn_finalize(const float* __restrict__ stats,
                              const float* __restrict__ g,
                              const float* __restrict__ b,
                              float* __restrict__ ss) {
    int j = threadIdx.x;
    if (j >= ND) return;
    float inv_n = 1.f / (float)N_NODES;
    float mu = stats[j] * inv_n;
    float var = stats[ND + j] * inv_n - mu * mu;
    float rs = rsqrtf(var + 1e-5f);
    float sc = rs * g[j];
    ss[j] = sc;
    ss[ND + j] = b[j] - mu * sc;
}

__global__ __launch_bounds__(256) void k_bn_apply(
    const float* __restrict__ t, const float* __restrict__ ss,
    float* __restrict__ h) {
    int idx = blockIdx.x * blockDim.x + threadIdx.x;
    int tot = N_NODES * ND;
    int stride = gridDim.x * blockDim.x;
    for (; idx < tot; idx += stride) {
        int c = idx & (ND - 1);
        h[idx] = t[idx] * ss[c] + ss[ND + c];
    }
}

// one wave per edge: z=[h_dst,h_src,e(recomputed)] in LDS; 2-layer MLP; atomic scatter
__global__ __launch_bounds__(256) void k_edge_conv(
    const float* __restrict__ h, const float* __restrict__ ea,
    const int* __restrict__ ei,
    const float* __restrict__ Wep, const float* __restrict__ bep,
    const float* __restrict__ We1, const float* __restrict__ be1,
    const float* __restrict__ We2, const float* __restrict__ be2,
    float* __restrict__ aggr) {
    __shared__ float zb[WPB][2 * ND + ED];
    __shared__ float pb[WPB][HD];
    int lane = threadIdx.x & 63;
    int wid = threadIdx.x >> 6;
    int e = blockIdx.x * WPB + wid;
    bool valid = e < N_EDGES;
    int ec = valid ? e : N_EDGES - 1;
    int src = ei[ec];             // edge_index[0] -> h[src] goes to z[64:128]
    int dst = ei[N_EDGES + ec];   // edge_index[1] -> h[dst] goes to z[0:64]
    zb[wid][lane] = h[dst * ND + lane];
    zb[wid][ND + lane] = h[src * ND + lane];
    if (lane < ED) {
        float a0 = ea[ec * 2], a1 = ea[ec * 2 + 1];
        zb[wid][2 * ND + lane] = sp(a0 * Wep[lane] + a1 * Wep[ED + lane] + bep[lane]);
    }
    __syncthreads();
    float h0 = be1[lane], h1 = be1[64 + lane];
#pragma unroll 8
    for (int k = 0; k < 2 * ND + ED; ++k) {
        float zk = zb[wid][k];
        h0 += zk * We1[k * HD + lane];
        h1 += zk * We1[k * HD + 64 + lane];
    }
    pb[wid][lane] = sp(h0);
    pb[wid][64 + lane] = sp(h1);
    __syncthreads();
    float o0 = be2[lane], o1 = be2[64 + lane];
#pragma unroll 8
    for (int k = 0; k < HD; ++k) {
        float pk = pb[wid][k];
        o0 += pk * We2[k * HD + lane];
        o1 += pk * We2[k * HD + 64 + lane];
    }
    if (valid) {
        atomicAdd(&aggr[dst * HD + lane], sp(o0));
        atomicAdd(&aggr[dst * HD + 64 + lane], sp(o1));
    }
}

// one wave per node: z2=[h,aggr]; hid=sp(z2@Wn1+bn1); tnew=hid@Wn2+bn2+h; stats
__global__ __launch_bounds__(256) void k_node_update(
    const float* __restrict__ h, const float* __restrict__ aggr,
    const float* __restrict__ Wn1, const float* __restrict__ bn1,
    const float* __restrict__ Wn2, const float* __restrict__ bn2,
    float* __restrict__ t, float* __restrict__ stats) {
    __shared__ float zb[WPB][ND + HD];
    __shared__ float pb[WPB][HD];
    int lane = threadIdx.x & 63;
    int wid = threadIdx.x >> 6;
    int wave = (blockIdx.x * blockDim.x + threadIdx.x) >> 6;
    int nw = (gridDim.x * blockDim.x) >> 6;
    int iters = (N_NODES + nw - 1) / nw;
    float s0 = 0.f, s1 = 0.f;
    for (int it = 0; it < iters; ++it) {
        int i = wave + it * nw;
        bool valid = i < N_NODES;
        int ic = valid ? i : N_NODES - 1;
        float hv = h[ic * ND + lane];
        zb[wid][lane] = hv;
        zb[wid][ND + lane] = aggr[ic * HD + lane];
        zb[wid][ND + 64 + lane] = aggr[ic * HD + 64 + lane];
        __syncthreads();
        float h0 = bn1[lane], h1 = bn1[64 + lane];
#pragma unroll 8
        for (int k = 0; k < ND + HD; ++k) {
            float zk = zb[wid][k];
            h0 += zk * Wn1[k * HD + lane];
            h1 += zk * Wn1[k * HD + 64 + lane];
        }
        pb[wid][lane] = sp(h0);
        pb[wid][64 + lane] = sp(h1);
        __syncthreads();
        float o = bn2[lane];
#pragma unroll 8
        for (int k = 0; k < HD; ++k) o += pb[wid][k] * Wn2[k * ND + lane];
        if (valid) {
            float tn = o + hv;
            t[ic * ND + lane] = tn;
            s0 += tn; s1 += tn * tn;
        }
        __syncthreads();
    }
    atomicAdd(&stats[lane], s0);
    atomicAdd(&stats[ND + lane], s1);
}

// mean-pool per graph using sorted batch: run-length local accumulation
__global__ __launch_bounds__(256) void k_pool(
    const float* __restrict__ h, const int* __restrict__ batch,
    float* __restrict__ pooled, float* __restrict__ cnt) {
    int lane = threadIdx.x & 63;
    int wave = (blockIdx.x * blockDim.x + threadIdx.x) >> 6;
    int nw = (gridDim.x * blockDim.x) >> 6;
    int chunk = (N_NODES + nw - 1) / nw;
    int s = wave * chunk;
    int epos = min(N_NODES, s + chunk);
    if (s >= N_NODES) return;
    int curg = batch[s];
    float acc = 0.f, c = 0.f;
    for (int i = s; i < epos; ++i) {
        int g = batch[i];
        if (g != curg) {
            atomicAdd(&pooled[curg * ND + lane], acc);
            if (lane == 0) atomicAdd(&cnt[curg], c);
            acc = 0.f; c = 0.f; curg = g;
        }
        acc += h[i * ND + lane];
        c += 1.f;
    }
    atomicAdd(&pooled[curg * ND + lane], acc);
    if (lane == 0) atomicAdd(&cnt[curg], c);
}

// one wave per graph: out = sp(pooled/cnt @ Wo1 + bo1) @ Wo2 + bo2
__global__ __launch_bounds__(256) void k_readout(
    const float* __restrict__ pooled, const float* __restrict__ cnt,
    const float* __restrict__ Wo1, const float* __restrict__ bo1,
    const float* __restrict__ Wo2, const float* __restrict__ bo2,
    float* __restrict__ out) {
    __shared__ float pbuf[WPB][ND];
    int lane = threadIdx.x & 63;
    int wid = threadIdx.x >> 6;
    int g = blockIdx.x * WPB + wid;
    bool valid = g < N_GRAPH;
    int gc = valid ? g : N_GRAPH - 1;
    float c = fmaxf(cnt[gc], 1.f);
    pbuf[wid][lane] = pooled[gc * ND + lane] / c;
    __syncthreads();
    float h0 = bo1[lane], h1 = bo1[64 + lane];
#pragma unroll 8
    for (int k = 0; k < ND; ++k) {
        float pk = pbuf[wid][k];
        h0 += pk * Wo1[k * HD + lane];
        h1 += pk * Wo1[k * HD + 64 + lane];
    }
    float s = sp(h0) * Wo2[lane] + sp(h1) * Wo2[64 + lane];
#pragma unroll
    for (int off = 32; off; off >>= 1) s += __shfl_down(s, off);
    if (valid && lane == 0) out[g] = s + bo2[0];
}

extern "C" void kernel_launch(void* const* d_in, const int* in_sizes, int n_in,
                              void* d_out, int out_size, void* d_ws, size_t ws_size,
                              hipStream_t stream) {
    const float* x       = (const float*)d_in[0];
    const float* ea      = (const float*)d_in[1];
    const int*   ei      = (const int*)d_in[2];
    const int*   batch   = (const int*)d_in[3];
    const float* Wnp     = (const float*)d_in[4];
    const float* bnp     = (const float*)d_in[5];
    const float* g_np    = (const float*)d_in[6];
    const float* be_np   = (const float*)d_in[7];
    const float* Wep     = (const float*)d_in[8];
    const float* bep     = (const float*)d_in[9];
    const float* We1     = (const float*)d_in[10];
    const float* be1     = (const float*)d_in[11];
    const float* We2     = (const float*)d_in[12];
    const float* be2     = (const float*)d_in[13];
    const float* Wn1     = (const float*)d_in[14];
    const float* bn1     = (const float*)d_in[15];
    const float* Wn2     = (const float*)d_in[16];
    const float* bn2     = (const float*)d_in[17];
    const float* g_bn    = (const float*)d_in[18];
    const float* b_bn    = (const float*)d_in[19];
    const float* Wo1     = (const float*)d_in[20];
    const float* bo1     = (const float*)d_in[21];
    const float* Wo2     = (const float*)d_in[22];
    const float* bo2     = (const float*)d_in[23];

    float* ws = (float*)d_ws;
    float* h      = ws;                       // N*64
    float* t      = h + N_NODES * ND;         // N*64
    float* aggr   = t + N_NODES * ND;         // N*128
    float* stats  = aggr + N_NODES * HD;      // 128
    float* ss     = stats + 2 * ND;           // 128
    float* pooled = ss + 2 * ND;              // G*64
    float* cnt    = pooled + N_GRAPH * ND;    // G

    float* outp = (float*)d_out;

    // node projection + BN
    hipMemsetAsync(stats, 0, 2 * ND * sizeof(float), stream);
    k_node_proj<<<512, 256, 0, stream>>>(x, Wnp, bnp, t, stats);
    k_bn_finalize<<<1, 64, 0, stream>>>(stats, g_np, be_np, ss);
    k_bn_apply<<<2048, 256, 0, stream>>>(t, ss, h);

    for (int l = 0; l < 3; ++l) {
        hipMemsetAsync(aggr, 0, (size_t)N_NODES * HD * sizeof(float), stream);
        k_edge_conv<<<(N_EDGES + WPB - 1) / WPB, 256, 0, stream>>>(
            h, ea, ei, Wep, bep,
            We1 + (size_t)l * (2 * ND + ED) * HD, be1 + l * HD,
            We2 + (size_t)l * HD * HD, be2 + l * HD, aggr);
        hipMemsetAsync(stats, 0, 2 * ND * sizeof(float), stream);
        k_node_update<<<512, 256, 0, stream>>>(
            h, aggr,
            Wn1 + (size_t)l * (ND + HD) * HD, bn1 + l * HD,
            Wn2 + (size_t)l * HD * ND, bn2 + l * ND, t, stats);
        k_bn_finalize<<<1, 64, 0, stream>>>(stats, g_bn + l * ND, b_bn + l * ND, ss);
        k_bn_apply<<<2048, 256, 0, stream>>>(t, ss, h);
    }

    // pooling + readout
    hipMemsetAsync(pooled, 0, (size_t)(N_GRAPH * ND + N_GRAPH) * sizeof(float), stream);
    k_pool<<<512, 256, 0, stream>>>(h, batch, pooled, cnt);
    k_readout<<<(N_GRAPH + WPB - 1) / WPB, 256, 0, stream>>>(
        pooled, cnt, Wo1, bo1, Wo2, bo2, outp);
}

// Round 4
// 5155.772 us; speedup vs baseline: 2.1271x; 2.1271x over previous
//
#include <hip/hip_runtime.h>
#include <hip/hip_bf16.h>

#define N_NODES 50000
#define N_EDGES 800000
#define N_GRAPH 500
#define ND 64
#define ED 32
#define HD 128
#define WPB 4   // waves per block (256 threads)

typedef __attribute__((ext_vector_type(8))) short bf16x8;
typedef __attribute__((ext_vector_type(4))) float f32x4;

__device__ __forceinline__ float sp(float x) {
    return fmaxf(x, 0.f) + log1pf(expf(-fabsf(x)));
}

__device__ __forceinline__ unsigned short f2bf(float v) {
    __hip_bfloat16 b = __float2bfloat16(v);
    return *(unsigned short*)&b;
}

__device__ __forceinline__ unsigned int pkbf(float a, float b) {
    return (unsigned int)f2bf(a) | ((unsigned int)f2bf(b) << 16);
}

// ---------------- node projection + BN (fp32, unchanged) ----------------
__global__ __launch_bounds__(256) void k_node_proj(
    const float* __restrict__ x, const float* __restrict__ Wnp,
    const float* __restrict__ bnp, float* __restrict__ t,
    float* __restrict__ stats) {
    int lane = threadIdx.x & 63;
    int wave = (blockIdx.x * blockDim.x + threadIdx.x) >> 6;
    int nw = (gridDim.x * blockDim.x) >> 6;
    float w[13];
#pragma unroll
    for (int k = 0; k < 13; ++k) w[k] = Wnp[k * ND + lane];
    float bb = bnp[lane];
    float s0 = 0.f, s1 = 0.f;
    for (int i = wave; i < N_NODES; i += nw) {
        float acc = bb;
#pragma unroll
        for (int k = 0; k < 13; ++k) acc += x[i * 13 + k] * w[k];
        float v = sp(acc);
        t[i * ND + lane] = v;
        s0 += v; s1 += v * v;
    }
    atomicAdd(&stats[lane], s0);
    atomicAdd(&stats[ND + lane], s1);
}

__global__ void k_bn_finalize(const float* __restrict__ stats,
                              const float* __restrict__ g,
                              const float* __restrict__ b,
                              float* __restrict__ ss) {
    int j = threadIdx.x;
    if (j >= ND) return;
    float inv_n = 1.f / (float)N_NODES;
    float mu = stats[j] * inv_n;
    float var = stats[ND + j] * inv_n - mu * mu;
    float rs = rsqrtf(var + 1e-5f);
    float sc = rs * g[j];
    ss[j] = sc;
    ss[ND + j] = b[j] - mu * sc;
}

// BN apply -> h fp32 AND h bf16 (for MFMA gathers)
__global__ __launch_bounds__(256) void k_bn_apply(
    const float* __restrict__ t, const float* __restrict__ ss,
    float* __restrict__ h, unsigned short* __restrict__ hb) {
    int idx = blockIdx.x * blockDim.x + threadIdx.x;
    int tot = N_NODES * ND;
    int stride = gridDim.x * blockDim.x;
    for (; idx < tot; idx += stride) {
        int c = idx & (ND - 1);
        float v = t[idx] * ss[c] + ss[ND + c];
        h[idx] = v;
        hb[idx] = f2bf(v);
    }
}

// ---------------- edge projection, precomputed once (bf16) --------------
__global__ __launch_bounds__(256) void k_eproj(
    const float* __restrict__ ea, const float* __restrict__ Wep,
    const float* __restrict__ bep, unsigned short* __restrict__ e_bf) {
    long idx = (long)blockIdx.x * blockDim.x + threadIdx.x;
    long tot = (long)N_EDGES * 32;
    if (idx >= tot) return;
    int e = (int)(idx >> 5), col = (int)(idx & 31);
    float v = sp(ea[2 * e] * Wep[col] + ea[2 * e + 1] * Wep[32 + col] + bep[col]);
    e_bf[idx] = f2bf(v);
}

// ---------------- weight pack: W[K][128] -> A-frag layout ---------------
// out[((ks*8+nf)*64 + l)*8 + r] = bf16(W[32ks + 8*(l>>4) + r][16nf + (l&15)])
__global__ __launch_bounds__(256) void k_pack_w(
    const float* __restrict__ W, unsigned short* __restrict__ out, int ksteps) {
    int tid = blockIdx.x * blockDim.x + threadIdx.x;
    int total = ksteps * 8 * 64;
    if (tid >= total) return;
    int l = tid & 63; int fr = tid >> 6; int nf = fr & 7; int ks = fr >> 3;
    int n = 16 * nf + (l & 15);
    int k0 = 32 * ks + 8 * (l >> 4);
#pragma unroll
    for (int r = 0; r < 8; ++r)
        out[tid * 8 + r] = f2bf(W[(k0 + r) * 128 + n]);
}

// ---------------- MFMA edge conv: fused 2-layer MLP + scatter -----------
// Per block: 128 edges. Per wave: 32 edges (2 m-frags), full N=128.
// GEMM1: D1^T[n][m] = We1^T @ Z^T, Z gathered from global bf16.
// P = sp(D1^T + be1) -> LDS (bf16, row stride 136).
// GEMM2: D2^T = We2^T @ P^T; m = sp(D2^T + be2) -> atomic scatter to aggr.
template <bool EPRE>
__global__ __launch_bounds__(256, 4) void k_edge_mfma(
    const unsigned short* __restrict__ h_bf, const unsigned short* __restrict__ e_bf,
    const float* __restrict__ ea, const float* __restrict__ Wep,
    const float* __restrict__ bep,
    const int* __restrict__ ei,
    const unsigned short* __restrict__ pA1, const float* __restrict__ be1,
    const unsigned short* __restrict__ pA2, const float* __restrict__ be2,
    float* __restrict__ aggr) {
    __shared__ unsigned short P[WPB][32][136];
    __shared__ unsigned short eL[EPRE ? 64 : 128 * 32];

    int lane = threadIdx.x & 63;
    int w = threadIdx.x >> 6;
    int m = lane & 15, g = lane >> 4;
    int ebase = blockIdx.x * 128;

    int eD0 = ei[N_EDGES + ebase + 32 * w + m];
    int eD1 = ei[N_EDGES + ebase + 32 * w + 16 + m];
    int eS0 = ei[ebase + 32 * w + m];
    int eS1 = ei[ebase + 32 * w + 16 + m];

    if constexpr (!EPRE) {
        // stage e for the 128-edge tile: thread -> (col, row0), 16 rows each
        int col = threadIdx.x & 31;
        int r0 = threadIdx.x >> 5;
        float w0 = Wep[col], w1 = Wep[32 + col], bb = bep[col];
#pragma unroll
        for (int i = 0; i < 16; ++i) {
            int em = r0 + 8 * i;
            int e = ebase + em;
            eL[em * 32 + col] = f2bf(sp(ea[2 * e] * w0 + ea[2 * e + 1] * w1 + bb));
        }
        __syncthreads();
    }

    f32x4 acc[2][8];
#pragma unroll
    for (int mf = 0; mf < 2; ++mf)
#pragma unroll
        for (int nf = 0; nf < 8; ++nf) acc[mf][nf] = (f32x4){0.f, 0.f, 0.f, 0.f};

    // ---- GEMM1: K = 160 (dst 64 | src 64 | e 32) ----
#pragma unroll
    for (int ks = 0; ks < 5; ++ks) {
        bf16x8 b0, b1;
        if (ks < 2) {
            b0 = *(const bf16x8*)(h_bf + (size_t)eD0 * 64 + ks * 32 + 8 * g);
            b1 = *(const bf16x8*)(h_bf + (size_t)eD1 * 64 + ks * 32 + 8 * g);
        } else if (ks < 4) {
            b0 = *(const bf16x8*)(h_bf + (size_t)eS0 * 64 + (ks - 2) * 32 + 8 * g);
            b1 = *(const bf16x8*)(h_bf + (size_t)eS1 * 64 + (ks - 2) * 32 + 8 * g);
        } else {
            if constexpr (EPRE) {
                b0 = *(const bf16x8*)(e_bf + (size_t)(ebase + 32 * w + m) * 32 + 8 * g);
                b1 = *(const bf16x8*)(e_bf + (size_t)(ebase + 32 * w + 16 + m) * 32 + 8 * g);
            } else {
                b0 = *(const bf16x8*)&eL[(32 * w + m) * 32 + 8 * g];
                b1 = *(const bf16x8*)&eL[(32 * w + 16 + m) * 32 + 8 * g];
            }
        }
#pragma unroll
        for (int nf = 0; nf < 8; ++nf) {
            bf16x8 a = *(const bf16x8*)(pA1 + ((ks * 8 + nf) * 64 + lane) * 8);
            acc[0][nf] = __builtin_amdgcn_mfma_f32_16x16x32_bf16(a, b0, acc[0][nf], 0, 0, 0);
            acc[1][nf] = __builtin_amdgcn_mfma_f32_16x16x32_bf16(a, b1, acc[1][nf], 0, 0, 0);
        }
    }

    // ---- epilogue 1: bias + softplus -> P (bf16) in LDS ----
#pragma unroll
    for (int nf = 0; nf < 8; ++nf) {
        f32x4 bb = *(const f32x4*)(be1 + 16 * nf + 4 * g);
#pragma unroll
        for (int mf = 0; mf < 2; ++mf) {
            f32x4 c = acc[mf][nf];
            unsigned int u01 = pkbf(sp(c[0] + bb[0]), sp(c[1] + bb[1]));
            unsigned int u23 = pkbf(sp(c[2] + bb[2]), sp(c[3] + bb[3]));
            unsigned int* dst = (unsigned int*)&P[w][m + 16 * mf][16 * nf + 4 * g];
            dst[0] = u01; dst[1] = u23;
        }
    }

    f32x4 acc2[2][8];
#pragma unroll
    for (int mf = 0; mf < 2; ++mf)
#pragma unroll
        for (int nf = 0; nf < 8; ++nf) acc2[mf][nf] = (f32x4){0.f, 0.f, 0.f, 0.f};

    // ---- GEMM2: K = 128, B = P^T from LDS (wave-private rows) ----
#pragma unroll
    for (int ks = 0; ks < 4; ++ks) {
        bf16x8 b0 = *(const bf16x8*)&P[w][m][32 * ks + 8 * g];
        bf16x8 b1 = *(const bf16x8*)&P[w][m + 16][32 * ks + 8 * g];
#pragma unroll
        for (int nf = 0; nf < 8; ++nf) {
            bf16x8 a = *(const bf16x8*)(pA2 + ((ks * 8 + nf) * 64 + lane) * 8);
            acc2[0][nf] = __builtin_amdgcn_mfma_f32_16x16x32_bf16(a, b0, acc2[0][nf], 0, 0, 0);
            acc2[1][nf] = __builtin_amdgcn_mfma_f32_16x16x32_bf16(a, b1, acc2[1][nf], 0, 0, 0);
        }
    }

    // ---- epilogue 2: bias + softplus -> atomic scatter ----
#pragma unroll
    for (int nf = 0; nf < 8; ++nf) {
        f32x4 bb = *(const f32x4*)(be2 + 16 * nf + 4 * g);
#pragma unroll
        for (int mf = 0; mf < 2; ++mf) {
            f32x4 c = acc2[mf][nf];
            int dst = mf ? eD1 : eD0;
            float* base = aggr + (size_t)dst * HD + 16 * nf + 4 * g;
            atomicAdd(base + 0, sp(c[0] + bb[0]));
            atomicAdd(base + 1, sp(c[1] + bb[1]));
            atomicAdd(base + 2, sp(c[2] + bb[2]));
            atomicAdd(base + 3, sp(c[3] + bb[3]));
        }
    }
}

// ---------------- node update (fp32, unchanged) -------------------------
__global__ __launch_bounds__(256) void k_node_update(
    const float* __restrict__ h, const float* __restrict__ aggr,
    const float* __restrict__ Wn1, const float* __restrict__ bn1,
    const float* __restrict__ Wn2, const float* __restrict__ bn2,
    float* __restrict__ t, float* __restrict__ stats) {
    __shared__ float zb[WPB][ND + HD];
    __shared__ float pb[WPB][HD];
    int lane = threadIdx.x & 63;
    int wid = threadIdx.x >> 6;
    int wave = (blockIdx.x * blockDim.x + threadIdx.x) >> 6;
    int nw = (gridDim.x * blockDim.x) >> 6;
    int iters = (N_NODES + nw - 1) / nw;
    float s0 = 0.f, s1 = 0.f;
    for (int it = 0; it < iters; ++it) {
        int i = wave + it * nw;
        bool valid = i < N_NODES;
        int ic = valid ? i : N_NODES - 1;
        float hv = h[ic * ND + lane];
        zb[wid][lane] = hv;
        zb[wid][ND + lane] = aggr[ic * HD + lane];
        zb[wid][ND + 64 + lane] = aggr[ic * HD + 64 + lane];
        __syncthreads();
        float h0 = bn1[lane], h1 = bn1[64 + lane];
#pragma unroll 8
        for (int k = 0; k < ND + HD; ++k) {
            float zk = zb[wid][k];
            h0 += zk * Wn1[k * HD + lane];
            h1 += zk * Wn1[k * HD + 64 + lane];
        }
        pb[wid][lane] = sp(h0);
        pb[wid][64 + lane] = sp(h1);
        __syncthreads();
        float o = bn2[lane];
#pragma unroll 8
        for (int k = 0; k < HD; ++k) o += pb[wid][k] * Wn2[k * ND + lane];
        if (valid) {
            float tn = o + hv;
            t[ic * ND + lane] = tn;
            s0 += tn; s1 += tn * tn;
        }
        __syncthreads();
    }
    atomicAdd(&stats[lane], s0);
    atomicAdd(&stats[ND + lane], s1);
}

// ---------------- pooling + readout (unchanged) -------------------------
__global__ __launch_bounds__(256) void k_pool(
    const float* __restrict__ h, const int* __restrict__ batch,
    float* __restrict__ pooled, float* __restrict__ cnt) {
    int lane = threadIdx.x & 63;
    int wave = (blockIdx.x * blockDim.x + threadIdx.x) >> 6;
    int nw = (gridDim.x * blockDim.x) >> 6;
    int chunk = (N_NODES + nw - 1) / nw;
    int s = wave * chunk;
    int epos = min(N_NODES, s + chunk);
    if (s >= N_NODES) return;
    int curg = batch[s];
    float acc = 0.f, c = 0.f;
    for (int i = s; i < epos; ++i) {
        int g = batch[i];
        if (g != curg) {
            atomicAdd(&pooled[curg * ND + lane], acc);
            if (lane == 0) atomicAdd(&cnt[curg], c);
            acc = 0.f; c = 0.f; curg = g;
        }
        acc += h[i * ND + lane];
        c += 1.f;
    }
    atomicAdd(&pooled[curg * ND + lane], acc);
    if (lane == 0) atomicAdd(&cnt[curg], c);
}

__global__ __launch_bounds__(256) void k_readout(
    const float* __restrict__ pooled, const float* __restrict__ cnt,
    const float* __restrict__ Wo1, const float* __restrict__ bo1,
    const float* __restrict__ Wo2, const float* __restrict__ bo2,
    float* __restrict__ out) {
    __shared__ float pbuf[WPB][ND];
    int lane = threadIdx.x & 63;
    int wid = threadIdx.x >> 6;
    int g = blockIdx.x * WPB + wid;
    bool valid = g < N_GRAPH;
    int gc = valid ? g : N_GRAPH - 1;
    float c = fmaxf(cnt[gc], 1.f);
    pbuf[wid][lane] = pooled[gc * ND + lane] / c;
    __syncthreads();
    float h0 = bo1[lane], h1 = bo1[64 + lane];
#pragma unroll 8
    for (int k = 0; k < ND; ++k) {
        float pk = pbuf[wid][k];
        h0 += pk * Wo1[k * HD + lane];
        h1 += pk * Wo1[k * HD + 64 + lane];
    }
    float s = sp(h0) * Wo2[lane] + sp(h1) * Wo2[64 + lane];
#pragma unroll
    for (int off = 32; off; off >>= 1) s += __shfl_down(s, off);
    if (valid && lane == 0) out[g] = s + bo2[0];
}

extern "C" void kernel_launch(void* const* d_in, const int* in_sizes, int n_in,
                              void* d_out, int out_size, void* d_ws, size_t ws_size,
                              hipStream_t stream) {
    const float* x       = (const float*)d_in[0];
    const float* ea      = (const float*)d_in[1];
    const int*   ei      = (const int*)d_in[2];
    const int*   batch   = (const int*)d_in[3];
    const float* Wnp     = (const float*)d_in[4];
    const float* bnp     = (const float*)d_in[5];
    const float* g_np    = (const float*)d_in[6];
    const float* be_np   = (const float*)d_in[7];
    const float* Wep     = (const float*)d_in[8];
    const float* bep     = (const float*)d_in[9];
    const float* We1     = (const float*)d_in[10];
    const float* be1     = (const float*)d_in[11];
    const float* We2     = (const float*)d_in[12];
    const float* be2     = (const float*)d_in[13];
    const float* Wn1     = (const float*)d_in[14];
    const float* bn1     = (const float*)d_in[15];
    const float* Wn2     = (const float*)d_in[16];
    const float* bn2     = (const float*)d_in[17];
    const float* g_bn    = (const float*)d_in[18];
    const float* b_bn    = (const float*)d_in[19];
    const float* Wo1     = (const float*)d_in[20];
    const float* bo1     = (const float*)d_in[21];
    const float* Wo2     = (const float*)d_in[22];
    const float* bo2     = (const float*)d_in[23];

    float* ws = (float*)d_ws;
    size_t off = 0;
    float* h      = ws + off; off += (size_t)N_NODES * ND;     // 3.2M
    float* t      = ws + off; off += (size_t)N_NODES * ND;     // 3.2M
    float* aggr   = ws + off; off += (size_t)N_NODES * HD;     // 6.4M
    float* stats  = ws + off; off += 2 * ND;
    float* ss     = ws + off; off += 2 * ND;
    float* pooled = ws + off; off += N_GRAPH * ND;
    float* cnt    = ws + off; off += N_GRAPH;                  // 500 (mult of 4)
    unsigned short* h_bf = (unsigned short*)(ws + off); off += (size_t)N_NODES * ND / 2;
    unsigned short* pA1  = (unsigned short*)(ws + off); off += 5 * 8 * 64 * 8 / 2;
    unsigned short* pA2  = (unsigned short*)(ws + off); off += 4 * 8 * 64 * 8 / 2;
    size_t base_bytes = off * sizeof(float);
    unsigned short* e_bf = (unsigned short*)(ws + off);
    bool epre = (ws_size >= base_bytes + (size_t)N_EDGES * 32 * 2);

    float* outp = (float*)d_out;

    // node projection + BN
    hipMemsetAsync(stats, 0, 2 * ND * sizeof(float), stream);
    k_node_proj<<<512, 256, 0, stream>>>(x, Wnp, bnp, t, stats);
    k_bn_finalize<<<1, 64, 0, stream>>>(stats, g_np, be_np, ss);
    k_bn_apply<<<2048, 256, 0, stream>>>(t, ss, h, h_bf);

    // edge projection, once (layer-invariant)
    if (epre)
        k_eproj<<<(int)(((long)N_EDGES * 32 + 255) / 256), 256, 0, stream>>>(ea, Wep, bep, e_bf);

    for (int l = 0; l < 3; ++l) {
        // pack this layer's edge-MLP weights into MFMA A-fragment order
        k_pack_w<<<(5 * 8 * 64 + 255) / 256, 256, 0, stream>>>(
            We1 + (size_t)l * 160 * HD, pA1, 5);
        k_pack_w<<<(4 * 8 * 64 + 255) / 256, 256, 0, stream>>>(
            We2 + (size_t)l * HD * HD, pA2, 4);

        hipMemsetAsync(aggr, 0, (size_t)N_NODES * HD * sizeof(float), stream);
        if (epre)
            k_edge_mfma<true><<<N_EDGES / 128, 256, 0, stream>>>(
                h_bf, e_bf, ea, Wep, bep, ei, pA1, be1 + l * HD, pA2, be2 + l * HD, aggr);
        else
            k_edge_mfma<false><<<N_EDGES / 128, 256, 0, stream>>>(
                h_bf, e_bf, ea, Wep, bep, ei, pA1, be1 + l * HD, pA2, be2 + l * HD, aggr);

        hipMemsetAsync(stats, 0, 2 * ND * sizeof(float), stream);
        k_node_update<<<512, 256, 0, stream>>>(
            h, aggr,
            Wn1 + (size_t)l * (ND + HD) * HD, bn1 + l * HD,
            Wn2 + (size_t)l * HD * ND, bn2 + l * ND, t, stats);
        k_bn_finalize<<<1, 64, 0, stream>>>(stats, g_bn + l * ND, b_bn + l * ND, ss);
        k_bn_apply<<<2048, 256, 0, stream>>>(t, ss, h, h_bf);
    }

    // pooling + readout
    hipMemsetAsync(pooled, 0, (size_t)(N_GRAPH * ND + N_GRAPH) * sizeof(float), stream);
    k_pool<<<512, 256, 0, stream>>>(h, batch, pooled, cnt);
    k_readout<<<(N_GRAPH + WPB - 1) / WPB, 256, 0, stream>>>(
        pooled, cnt, Wo1, bo1, Wo2, bo2, outp);
}

// Round 6
// 2871.699 us; speedup vs baseline: 3.8190x; 1.7954x over previous
//
#include <hip/hip_runtime.h>
#include <hip/hip_bf16.h>

#define N_NODES 50000
#define N_EDGES 800000
#define N_GRAPH 500
#define ND 64
#define ED 32
#define HD 128
#define WPB 4   // waves per block (256 threads)

typedef __attribute__((ext_vector_type(8))) short bf16x8;
typedef __attribute__((ext_vector_type(4))) float f32x4;

__device__ __forceinline__ float sp(float x) {
    return fmaxf(x, 0.f) + log1pf(expf(-fabsf(x)));
}

__device__ __forceinline__ unsigned short f2bf(float v) {
    __hip_bfloat16 b = __float2bfloat16(v);
    return *(unsigned short*)&b;
}

__device__ __forceinline__ unsigned int pkbf(float a, float b) {
    return (unsigned int)f2bf(a) | ((unsigned int)f2bf(b) << 16);
}

// ---------------- node projection + BN (fp32) ---------------------------
__global__ __launch_bounds__(256) void k_node_proj(
    const float* __restrict__ x, const float* __restrict__ Wnp,
    const float* __restrict__ bnp, float* __restrict__ t,
    float* __restrict__ stats) {
    int lane = threadIdx.x & 63;
    int wave = (blockIdx.x * blockDim.x + threadIdx.x) >> 6;
    int nw = (gridDim.x * blockDim.x) >> 6;
    float w[13];
#pragma unroll
    for (int k = 0; k < 13; ++k) w[k] = Wnp[k * ND + lane];
    float bb = bnp[lane];
    float s0 = 0.f, s1 = 0.f;
    for (int i = wave; i < N_NODES; i += nw) {
        float acc = bb;
#pragma unroll
        for (int k = 0; k < 13; ++k) acc += x[i * 13 + k] * w[k];
        float v = sp(acc);
        t[i * ND + lane] = v;
        s0 += v; s1 += v * v;
    }
    atomicAdd(&stats[lane], s0);
    atomicAdd(&stats[ND + lane], s1);
}

__global__ void k_bn_finalize(const float* __restrict__ stats,
                              const float* __restrict__ g,
                              const float* __restrict__ b,
                              float* __restrict__ ss) {
    int j = threadIdx.x;
    if (j >= ND) return;
    float inv_n = 1.f / (float)N_NODES;
    float mu = stats[j] * inv_n;
    float var = stats[ND + j] * inv_n - mu * mu;
    float rs = rsqrtf(var + 1e-5f);
    float sc = rs * g[j];
    ss[j] = sc;
    ss[ND + j] = b[j] - mu * sc;
}

__global__ __launch_bounds__(256) void k_bn_apply(
    const float* __restrict__ t, const float* __restrict__ ss,
    float* __restrict__ h, unsigned short* __restrict__ hb) {
    int idx = blockIdx.x * blockDim.x + threadIdx.x;
    int tot = N_NODES * ND;
    int stride = gridDim.x * blockDim.x;
    for (; idx < tot; idx += stride) {
        int c = idx & (ND - 1);
        float v = t[idx] * ss[c] + ss[ND + c];
        h[idx] = v;
        hb[idx] = f2bf(v);
    }
}

// ---------------- counting sort of edges by dst -------------------------
__global__ __launch_bounds__(256) void k_hist(const int* __restrict__ ei,
                                              int* __restrict__ hist) {
    int e = blockIdx.x * 256 + threadIdx.x;
    if (e < N_EDGES) atomicAdd(&hist[ei[N_EDGES + e]], 1);
}

__global__ __launch_bounds__(1024) void k_scan1(const int* __restrict__ hist,
                                                int* __restrict__ chunksum) {
    __shared__ int s[1024];
    int t = threadIdx.x;
    int i = blockIdx.x * 1024 + t;
    s[t] = (i < N_NODES) ? hist[i] : 0;
    __syncthreads();
    for (int off = 512; off; off >>= 1) {
        if (t < off) s[t] += s[t + off];
        __syncthreads();
    }
    if (t == 0) chunksum[blockIdx.x] = s[0];
}

__global__ void k_scan2(int* __restrict__ chunksum, int n) {
    if (threadIdx.x == 0) {
        int acc = 0;
        for (int i = 0; i < n; ++i) { int v = chunksum[i]; chunksum[i] = acc; acc += v; }
    }
}

__global__ __launch_bounds__(1024) void k_scan3(const int* __restrict__ hist,
                                                const int* __restrict__ chunksum,
                                                int* __restrict__ cursor) {
    __shared__ int s[1024];
    int t = threadIdx.x;
    int i = blockIdx.x * 1024 + t;
    int v = (i < N_NODES) ? hist[i] : 0;
    s[t] = v;
    __syncthreads();
    for (int off = 1; off < 1024; off <<= 1) {
        int u = (t >= off) ? s[t - off] : 0;
        __syncthreads();
        s[t] += u;
        __syncthreads();
    }
    if (i < N_NODES) cursor[i] = chunksum[blockIdx.x] + s[t] - v;  // exclusive
}

__global__ __launch_bounds__(256) void k_scatter(const int* __restrict__ ei,
                                                 int* __restrict__ cursor,
                                                 int* __restrict__ sD,
                                                 int* __restrict__ sS,
                                                 int* __restrict__ sE) {
    int e = blockIdx.x * 256 + threadIdx.x;
    if (e >= N_EDGES) return;
    int d = ei[N_EDGES + e];
    int pos = atomicAdd(&cursor[d], 1);
    sD[pos] = d;
    sS[pos] = ei[e];
    sE[pos] = e;
}

// edge projection into sorted order (layer-invariant, once per call)
__global__ __launch_bounds__(256) void k_eproj_sorted(
    const float* __restrict__ ea, const int* __restrict__ sE,
    const float* __restrict__ Wep, const float* __restrict__ bep,
    unsigned short* __restrict__ e_bf) {
    long idx = (long)blockIdx.x * blockDim.x + threadIdx.x;
    long tot = (long)N_EDGES * 32;
    if (idx >= tot) return;
    int p = (int)(idx >> 5), col = (int)(idx & 31);
    int e = sE[p];
    float v = sp(ea[2 * e] * Wep[col] + ea[2 * e + 1] * Wep[32 + col] + bep[col]);
    e_bf[idx] = f2bf(v);
}

// ---------------- weight pack: W[K][128] -> A-frag layout ---------------
__global__ __launch_bounds__(256) void k_pack_w(
    const float* __restrict__ W, unsigned short* __restrict__ out, int ksteps) {
    int tid = blockIdx.x * blockDim.x + threadIdx.x;
    int total = ksteps * 8 * 64;
    if (tid >= total) return;
    int l = tid & 63; int fr = tid >> 6; int nf = fr & 7; int ks = fr >> 3;
    int n = 16 * nf + (l & 15);
    int k0 = 32 * ks + 8 * (l >> 4);
#pragma unroll
    for (int r = 0; r < 8; ++r)
        out[tid * 8 + r] = f2bf(W[(k0 + r) * 128 + n]);
}

// ---------------- MFMA edge conv on dst-sorted edges --------------------
// Per block: 128 sorted edges. Per wave: 32 edges. Epilogue stages results
// fp32 in LDS (reusing P) and does run-length segmented reduction: one
// atomicAdd per (run, channel) instead of per (edge, channel).
template <bool EPRE>
__global__ __launch_bounds__(256, 4) void k_edge_mfma_s(
    const unsigned short* __restrict__ h_bf, const unsigned short* __restrict__ e_bf,
    const float* __restrict__ ea, const int* __restrict__ sE,
    const float* __restrict__ Wep, const float* __restrict__ bep,
    const int* __restrict__ sD, const int* __restrict__ sS,
    const unsigned short* __restrict__ pA1, const float* __restrict__ be1,
    const unsigned short* __restrict__ pA2, const float* __restrict__ be2,
    float* __restrict__ aggr) {
    __shared__ unsigned short P[WPB][32][136];   // bf16 P; reused as fp32 stage
    __shared__ int dstS[WPB][16];
    __shared__ unsigned short eL[EPRE ? 64 : 128 * 32];

    int lane = threadIdx.x & 63;
    int w = threadIdx.x >> 6;
    int m = lane & 15, g = lane >> 4;
    int tile0 = blockIdx.x * 128;
    int wbase = tile0 + 32 * w;

    int eD0 = sD[wbase + m];
    int eD1 = sD[wbase + 16 + m];
    int eS0 = sS[wbase + m];
    int eS1 = sS[wbase + 16 + m];

    if constexpr (!EPRE) {
        int col = threadIdx.x & 31;
        int r0 = threadIdx.x >> 5;
        float w0 = Wep[col], w1 = Wep[32 + col], bb = bep[col];
#pragma unroll
        for (int i = 0; i < 16; ++i) {
            int em = r0 + 8 * i;
            int e = sE[tile0 + em];
            eL[em * 32 + col] = f2bf(sp(ea[2 * e] * w0 + ea[2 * e + 1] * w1 + bb));
        }
        __syncthreads();
    }

    f32x4 acc[2][8];
#pragma unroll
    for (int mf = 0; mf < 2; ++mf)
#pragma unroll
        for (int nf = 0; nf < 8; ++nf) acc[mf][nf] = (f32x4){0.f, 0.f, 0.f, 0.f};

    // ---- GEMM1: K = 160 (dst 64 | src 64 | e 32) ----
#pragma unroll
    for (int ks = 0; ks < 5; ++ks) {
        bf16x8 b0, b1;
        if (ks < 2) {
            b0 = *(const bf16x8*)(h_bf + (size_t)eD0 * 64 + ks * 32 + 8 * g);
            b1 = *(const bf16x8*)(h_bf + (size_t)eD1 * 64 + ks * 32 + 8 * g);
        } else if (ks < 4) {
            b0 = *(const bf16x8*)(h_bf + (size_t)eS0 * 64 + (ks - 2) * 32 + 8 * g);
            b1 = *(const bf16x8*)(h_bf + (size_t)eS1 * 64 + (ks - 2) * 32 + 8 * g);
        } else {
            if constexpr (EPRE) {
                b0 = *(const bf16x8*)(e_bf + (size_t)(wbase + m) * 32 + 8 * g);
                b1 = *(const bf16x8*)(e_bf + (size_t)(wbase + 16 + m) * 32 + 8 * g);
            } else {
                b0 = *(const bf16x8*)&eL[(32 * w + m) * 32 + 8 * g];
                b1 = *(const bf16x8*)&eL[(32 * w + 16 + m) * 32 + 8 * g];
            }
        }
#pragma unroll
        for (int nf = 0; nf < 8; ++nf) {
            bf16x8 a = *(const bf16x8*)(pA1 + ((ks * 8 + nf) * 64 + lane) * 8);
            acc[0][nf] = __builtin_amdgcn_mfma_f32_16x16x32_bf16(a, b0, acc[0][nf], 0, 0, 0);
            acc[1][nf] = __builtin_amdgcn_mfma_f32_16x16x32_bf16(a, b1, acc[1][nf], 0, 0, 0);
        }
    }

    // ---- epilogue 1: bias + softplus -> P (bf16) in LDS ----
#pragma unroll
    for (int nf = 0; nf < 8; ++nf) {
        f32x4 bb = *(const f32x4*)(be1 + 16 * nf + 4 * g);
#pragma unroll
        for (int mf = 0; mf < 2; ++mf) {
            f32x4 c = acc[mf][nf];
            unsigned int u01 = pkbf(sp(c[0] + bb[0]), sp(c[1] + bb[1]));
            unsigned int u23 = pkbf(sp(c[2] + bb[2]), sp(c[3] + bb[3]));
            unsigned int* dst = (unsigned int*)&P[w][m + 16 * mf][16 * nf + 4 * g];
            dst[0] = u01; dst[1] = u23;
        }
    }

    f32x4 acc2[2][8];
#pragma unroll
    for (int mf = 0; mf < 2; ++mf)
#pragma unroll
        for (int nf = 0; nf < 8; ++nf) acc2[mf][nf] = (f32x4){0.f, 0.f, 0.f, 0.f};

    // ---- GEMM2: K = 128, B = P^T from LDS (wave-private rows) ----
#pragma unroll
    for (int ks = 0; ks < 4; ++ks) {
        bf16x8 b0 = *(const bf16x8*)&P[w][m][32 * ks + 8 * g];
        bf16x8 b1 = *(const bf16x8*)&P[w][m + 16][32 * ks + 8 * g];
#pragma unroll
        for (int nf = 0; nf < 8; ++nf) {
            bf16x8 a = *(const bf16x8*)(pA2 + ((ks * 8 + nf) * 64 + lane) * 8);
            acc2[0][nf] = __builtin_amdgcn_mfma_f32_16x16x32_bf16(a, b0, acc2[0][nf], 0, 0, 0);
            acc2[1][nf] = __builtin_amdgcn_mfma_f32_16x16x32_bf16(a, b1, acc2[1][nf], 0, 0, 0);
        }
    }

    __syncthreads();  // fence: P (bf16) reads done before fp32 reuse

    // ---- epilogue 2: stage fp32 rows, run-length segmented reduce ------
    float* st = (float*)&P[w][0][0];  // 16 rows x 132 floats = 8448B <= 8704B
#pragma unroll 1
    for (int mf = 0; mf < 2; ++mf) {
        int d = mf ? eD1 : eD0;
        dstS[w][m] = d;  // all g write same value
#pragma unroll
        for (int nf = 0; nf < 8; ++nf) {
            f32x4 bb = *(const f32x4*)(be2 + 16 * nf + 4 * g);
            f32x4 c = acc2[mf][nf];
            f32x4 v = { sp(c[0] + bb[0]), sp(c[1] + bb[1]),
                        sp(c[2] + bb[2]), sp(c[3] + bb[3]) };
            *(f32x4*)&st[m * 132 + 16 * nf + 4 * g] = v;
        }
        asm volatile("" ::: "memory");
        float a0 = 0.f, a1 = 0.f;
        int cur = dstS[w][0];
#pragma unroll 1
        for (int r = 0; r < 16; ++r) {
            int dr = dstS[w][r];               // wave-uniform
            if (dr != cur) {                   // uniform branch
                atomicAdd(&aggr[(size_t)cur * HD + lane], a0);
                atomicAdd(&aggr[(size_t)cur * HD + 64 + lane], a1);
                a0 = 0.f; a1 = 0.f; cur = dr;
            }
            a0 += st[r * 132 + lane];
            a1 += st[r * 132 + 64 + lane];
        }
        atomicAdd(&aggr[(size_t)cur * HD + lane], a0);
        atomicAdd(&aggr[(size_t)cur * HD + 64 + lane], a1);
        asm volatile("" ::: "memory");
    }
}

// ---------------- node update (fp32, unchanged) -------------------------
__global__ __launch_bounds__(256) void k_node_update(
    const float* __restrict__ h, const float* __restrict__ aggr,
    const float* __restrict__ Wn1, const float* __restrict__ bn1,
    const float* __restrict__ Wn2, const float* __restrict__ bn2,
    float* __restrict__ t, float* __restrict__ stats) {
    __shared__ float zb[WPB][ND + HD];
    __shared__ float pb[WPB][HD];
    int lane = threadIdx.x & 63;
    int wid = threadIdx.x >> 6;
    int wave = (blockIdx.x * blockDim.x + threadIdx.x) >> 6;
    int nw = (gridDim.x * blockDim.x) >> 6;
    int iters = (N_NODES + nw - 1) / nw;
    float s0 = 0.f, s1 = 0.f;
    for (int it = 0; it < iters; ++it) {
        int i = wave + it * nw;
        bool valid = i < N_NODES;
        int ic = valid ? i : N_NODES - 1;
        float hv = h[ic * ND + lane];
        zb[wid][lane] = hv;
        zb[wid][ND + lane] = aggr[ic * HD + lane];
        zb[wid][ND + 64 + lane] = aggr[ic * HD + 64 + lane];
        __syncthreads();
        float h0 = bn1[lane], h1 = bn1[64 + lane];
#pragma unroll 8
        for (int k = 0; k < ND + HD; ++k) {
            float zk = zb[wid][k];
            h0 += zk * Wn1[k * HD + lane];
            h1 += zk * Wn1[k * HD + 64 + lane];
        }
        pb[wid][lane] = sp(h0);
        pb[wid][64 + lane] = sp(h1);
        __syncthreads();
        float o = bn2[lane];
#pragma unroll 8
        for (int k = 0; k < HD; ++k) o += pb[wid][k] * Wn2[k * ND + lane];
        if (valid) {
            float tn = o + hv;
            t[ic * ND + lane] = tn;
            s0 += tn; s1 += tn * tn;
        }
        __syncthreads();
    }
    atomicAdd(&stats[lane], s0);
    atomicAdd(&stats[ND + lane], s1);
}

// ---------------- pooling + readout (unchanged) -------------------------
__global__ __launch_bounds__(256) void k_pool(
    const float* __restrict__ h, const int* __restrict__ batch,
    float* __restrict__ pooled, float* __restrict__ cnt) {
    int lane = threadIdx.x & 63;
    int wave = (blockIdx.x * blockDim.x + threadIdx.x) >> 6;
    int nw = (gridDim.x * blockDim.x) >> 6;
    int chunk = (N_NODES + nw - 1) / nw;
    int s = wave * chunk;
    int epos = min(N_NODES, s + chunk);
    if (s >= N_NODES) return;
    int curg = batch[s];
    float acc = 0.f, c = 0.f;
    for (int i = s; i < epos; ++i) {
        int g = batch[i];
        if (g != curg) {
            atomicAdd(&pooled[curg * ND + lane], acc);
            if (lane == 0) atomicAdd(&cnt[curg], c);
            acc = 0.f; c = 0.f; curg = g;
        }
        acc += h[i * ND + lane];
        c += 1.f;
    }
    atomicAdd(&pooled[curg * ND + lane], acc);
    if (lane == 0) atomicAdd(&cnt[curg], c);
}

__global__ __launch_bounds__(256) void k_readout(
    const float* __restrict__ pooled, const float* __restrict__ cnt,
    const float* __restrict__ Wo1, const float* __restrict__ bo1,
    const float* __restrict__ Wo2, const float* __restrict__ bo2,
    float* __restrict__ out) {
    __shared__ float pbuf[WPB][ND];
    int lane = threadIdx.x & 63;
    int wid = threadIdx.x >> 6;
    int g = blockIdx.x * WPB + wid;
    bool valid = g < N_GRAPH;
    int gc = valid ? g : N_GRAPH - 1;
    float c = fmaxf(cnt[gc], 1.f);
    pbuf[wid][lane] = pooled[gc * ND + lane] / c;
    __syncthreads();
    float h0 = bo1[lane], h1 = bo1[64 + lane];
#pragma unroll 8
    for (int k = 0; k < ND; ++k) {
        float pk = pbuf[wid][k];
        h0 += pk * Wo1[k * HD + lane];
        h1 += pk * Wo1[k * HD + 64 + lane];
    }
    float s = sp(h0) * Wo2[lane] + sp(h1) * Wo2[64 + lane];
#pragma unroll
    for (int off = 32; off; off >>= 1) s += __shfl_down(s, off);
    if (valid && lane == 0) out[g] = s + bo2[0];
}

extern "C" void kernel_launch(void* const* d_in, const int* in_sizes, int n_in,
                              void* d_out, int out_size, void* d_ws, size_t ws_size,
                              hipStream_t stream) {
    const float* x       = (const float*)d_in[0];
    const float* ea      = (const float*)d_in[1];
    const int*   ei      = (const int*)d_in[2];
    const int*   batch   = (const int*)d_in[3];
    const float* Wnp     = (const float*)d_in[4];
    const float* bnp     = (const float*)d_in[5];
    const float* g_np    = (const float*)d_in[6];
    const float* be_np   = (const float*)d_in[7];
    const float* Wep     = (const float*)d_in[8];
    const float* bep     = (const float*)d_in[9];
    const float* We1     = (const float*)d_in[10];
    const float* be1     = (const float*)d_in[11];
    const float* We2     = (const float*)d_in[12];
    const float* be2     = (const float*)d_in[13];
    const float* Wn1     = (const float*)d_in[14];
    const float* bn1     = (const float*)d_in[15];
    const float* Wn2     = (const float*)d_in[16];
    const float* bn2     = (const float*)d_in[17];
    const float* g_bn    = (const float*)d_in[18];
    const float* b_bn    = (const float*)d_in[19];
    const float* Wo1     = (const float*)d_in[20];
    const float* bo1     = (const float*)d_in[21];
    const float* Wo2     = (const float*)d_in[22];
    const float* bo2     = (const float*)d_in[23];

    float* ws = (float*)d_ws;
    size_t off = 0;
    float* h      = ws + off; off += (size_t)N_NODES * ND;
    float* t      = ws + off; off += (size_t)N_NODES * ND;
    float* aggr   = ws + off; off += (size_t)N_NODES * HD;
    float* stats  = ws + off; off += 2 * ND;
    float* ss     = ws + off; off += 2 * ND;
    float* pooled = ws + off; off += N_GRAPH * ND;
    float* cnt    = ws + off; off += 512;
    unsigned short* h_bf = (unsigned short*)(ws + off); off += (size_t)N_NODES * ND / 2;
    unsigned short* pA1  = (unsigned short*)(ws + off); off += 5 * 8 * 64 * 8 / 2;
    unsigned short* pA2  = (unsigned short*)(ws + off); off += 4 * 8 * 64 * 8 / 2;
    int* sD       = (int*)(ws + off); off += N_EDGES;
    int* sS       = (int*)(ws + off); off += N_EDGES;
    int* sE       = (int*)(ws + off); off += N_EDGES;
    int* hist     = (int*)(ws + off); off += N_NODES;
    int* cursor   = (int*)(ws + off); off += N_NODES;
    int* chunksum = (int*)(ws + off); off += 64;
    size_t base_bytes = off * sizeof(float);
    unsigned short* e_bf = (unsigned short*)(ws + off);
    bool epre = (ws_size >= base_bytes + (size_t)N_EDGES * 32 * 2);

    float* outp = (float*)d_out;

    const int NCH = (N_NODES + 1023) / 1024;  // 49

    // ---- counting sort of edges by dst (once per call) ----
    hipMemsetAsync(hist, 0, N_NODES * sizeof(int), stream);
    k_hist<<<(N_EDGES + 255) / 256, 256, 0, stream>>>(ei, hist);
    k_scan1<<<NCH, 1024, 0, stream>>>(hist, chunksum);
    k_scan2<<<1, 64, 0, stream>>>(chunksum, NCH);
    k_scan3<<<NCH, 1024, 0, stream>>>(hist, chunksum, cursor);
    k_scatter<<<(N_EDGES + 255) / 256, 256, 0, stream>>>(ei, cursor, sD, sS, sE);
    if (epre)
        k_eproj_sorted<<<(int)(((long)N_EDGES * 32 + 255) / 256), 256, 0, stream>>>(
            ea, sE, Wep, bep, e_bf);

    // ---- node projection + BN ----
    hipMemsetAsync(stats, 0, 2 * ND * sizeof(float), stream);
    k_node_proj<<<512, 256, 0, stream>>>(x, Wnp, bnp, t, stats);
    k_bn_finalize<<<1, 64, 0, stream>>>(stats, g_np, be_np, ss);
    k_bn_apply<<<2048, 256, 0, stream>>>(t, ss, h, h_bf);

    for (int l = 0; l < 3; ++l) {
        k_pack_w<<<(5 * 8 * 64 + 255) / 256, 256, 0, stream>>>(
            We1 + (size_t)l * 160 * HD, pA1, 5);
        k_pack_w<<<(4 * 8 * 64 + 255) / 256, 256, 0, stream>>>(
            We2 + (size_t)l * HD * HD, pA2, 4);

        hipMemsetAsync(aggr, 0, (size_t)N_NODES * HD * sizeof(float), stream);
        if (epre)
            k_edge_mfma_s<true><<<N_EDGES / 128, 256, 0, stream>>>(
                h_bf, e_bf, ea, sE, Wep, bep, sD, sS,
                pA1, be1 + l * HD, pA2, be2 + l * HD, aggr);
        else
            k_edge_mfma_s<false><<<N_EDGES / 128, 256, 0, stream>>>(
                h_bf, e_bf, ea, sE, Wep, bep, sD, sS,
                pA1, be1 + l * HD, pA2, be2 + l * HD, aggr);

        hipMemsetAsync(stats, 0, 2 * ND * sizeof(float), stream);
        k_node_update<<<512, 256, 0, stream>>>(
            h, aggr,
            Wn1 + (size_t)l * (ND + HD) * HD, bn1 + l * HD,
            Wn2 + (size_t)l * HD * ND, bn2 + l * ND, t, stats);
        k_bn_finalize<<<1, 64, 0, stream>>>(stats, g_bn + l * ND, b_bn + l * ND, ss);
        k_bn_apply<<<2048, 256, 0, stream>>>(t, ss, h, h_bf);
    }

    hipMemsetAsync(pooled, 0, (size_t)(N_GRAPH * ND + 512) * sizeof(float), stream);
    k_pool<<<512, 256, 0, stream>>>(h, batch, pooled, cnt);
    k_readout<<<(N_GRAPH + WPB - 1) / WPB, 256, 0, stream>>>(
        pooled, cnt, Wo1, bo1, Wo2, bo2, outp);
}